// Round 5
// baseline (67.064 us; speedup 1.0000x reference)
//
#include <hip/hip_runtime.h>

#define NROWS 8192
#define NC 64
#define INVT 2.0f      // 1 / TEMPERATURE
#define LMBDA 0.5f
#define JSPLIT 16
#define TJ 64
#define PITCH 72       // LDS row pitch in bf16 elems (144 B)
#define LN2F 0.69314718055994531f
#define L2EF 1.4426950408889634f
#define KHI 110.0f     // global log2-domain shift: exp2(dot_scaled - KHI)

typedef __attribute__((ext_vector_type(8))) short short8;
typedef __attribute__((ext_vector_type(4))) float f32x4;

// ---------------- workspace layout (float slots) ----------------
#define WS_S     0                        // 64x64 class sums
#define WS_CNT   4096                     // 64 ints
#define WS_CE    4160
#define WS_SC    4161
#define WS_DONE  4162
#define WS_SPART 4224                     // JSPLIT * 8192 floats
#define WS_XB    (WS_SPART + JSPLIT*NROWS)  // 8192*64 ushort
#define WS_ZERO_F4 1041                   // ceil(4163/4) float4s

__device__ inline ushort f2bf(float f) {
  uint b = __float_as_uint(f);
  return (ushort)((b + 0x7fffu + ((b >> 16) & 1u)) >> 16);
}

// ---- zero the accumulator scalars / S / cnt ----
__global__ void k_zero(float* __restrict__ ws) {
  int i = blockIdx.x * 256 + threadIdx.x;
  if (i < WS_ZERO_F4) ((float4*)ws)[i] = make_float4(0.f, 0.f, 0.f, 0.f);
}

// ---- fused: bf16 convert (scaled), class sums/counts, cross entropy ----
__global__ __launch_bounds__(256) void k_pre(const float* __restrict__ x,
                                             const int* __restrict__ tgt,
                                             ushort* __restrict__ xb,
                                             float* __restrict__ S,
                                             int* __restrict__ cnt,
                                             float* __restrict__ ce_sum) {
  __shared__ float Sl[NC * NC];
  __shared__ int cl[NC];
  int t = threadIdx.x;
  for (int i = t; i < NC * NC; i += 256) Sl[i] = 0.0f;
  if (t < NC) cl[t] = 0;
  __syncthreads();

  int r4 = t >> 2, q = t & 3;            // 4 threads per row, 16 floats each
  int row = blockIdx.x * 64 + r4;
  int lbl = tgt[row];
  const float* xp = x + (size_t)row * NC + q * 16;
  float4 b[4];
#pragma unroll
  for (int k = 0; k < 4; ++k) b[k] = ((const float4*)xp)[k];

  // scaled bf16: xs = x * sqrt(INVT * log2(e))
  const float c = 1.6986436005760381f;
  ushort us[16];
#pragma unroll
  for (int k = 0; k < 4; ++k) {
    us[k * 4 + 0] = f2bf(b[k].x * c); us[k * 4 + 1] = f2bf(b[k].y * c);
    us[k * 4 + 2] = f2bf(b[k].z * c); us[k * 4 + 3] = f2bf(b[k].w * c);
  }
  ushort* xq = xb + (size_t)row * NC + q * 16;
  ((short8*)xq)[0] = ((const short8*)us)[0];
  ((short8*)xq)[1] = ((const short8*)us)[1];

  // class sums (LDS atomics)
#pragma unroll
  for (int k = 0; k < 4; ++k) {
    int c0 = q * 16 + k * 4;
    atomicAdd(&Sl[lbl * NC + c0 + 0], b[k].x);
    atomicAdd(&Sl[lbl * NC + c0 + 1], b[k].y);
    atomicAdd(&Sl[lbl * NC + c0 + 2], b[k].z);
    atomicAdd(&Sl[lbl * NC + c0 + 3], b[k].w);
  }
  if (q == 0) atomicAdd(&cl[lbl], 1);

  // cross entropy (4 threads per row), base-2 domain
  float m = -1e30f;
#pragma unroll
  for (int k = 0; k < 4; ++k)
    m = fmaxf(m, fmaxf(fmaxf(b[k].x, b[k].y), fmaxf(b[k].z, b[k].w)));
  m = fmaxf(m, __shfl_xor(m, 1));
  m = fmaxf(m, __shfl_xor(m, 2));
  float mb = m * L2EF;
  float s = 0.0f, tl = 0.0f;
#pragma unroll
  for (int k = 0; k < 4; ++k) {
    s += __builtin_amdgcn_exp2f(fmaf(b[k].x, L2EF, -mb)) +
         __builtin_amdgcn_exp2f(fmaf(b[k].y, L2EF, -mb)) +
         __builtin_amdgcn_exp2f(fmaf(b[k].z, L2EF, -mb)) +
         __builtin_amdgcn_exp2f(fmaf(b[k].w, L2EF, -mb));
    int c0 = q * 16 + k * 4;
    if (lbl == c0 + 0) tl = b[k].x;
    if (lbl == c0 + 1) tl = b[k].y;
    if (lbl == c0 + 2) tl = b[k].z;
    if (lbl == c0 + 3) tl = b[k].w;
  }
  s += __shfl_xor(s, 1);  s += __shfl_xor(s, 2);
  tl += __shfl_xor(tl, 1); tl += __shfl_xor(tl, 2);
  float ce = (q == 0) ? (m + LN2F * __log2f(s) - tl) : 0.0f;
#pragma unroll
  for (int msk = 32; msk >= 1; msk >>= 1) ce += __shfl_xor(ce, msk);
  if ((t & 63) == 0) atomicAdd(ce_sum, ce);

  __syncthreads();
  for (int i = t; i < NC * NC; i += 256) atomicAdd(&S[i], Sl[i]);
  if (t < NC && cl[t]) atomicAdd(&cnt[t], cl[t]);
}

// ---- main pass: MFMA sim tiles, global-K exp2 sum ----
// LDS chunk XOR-swizzle: chunk' = chunk ^ (row & 7)  (write & read consistent)
__global__ __launch_bounds__(256) void k_sim(const ushort* __restrict__ xb,
                                             float* __restrict__ spart) {
  __shared__ ushort Xj[TJ * PITCH];
  int t = threadIdx.x;
  int bid = blockIdx.x;
  int ib = bid & 127;      // 128 i-blocks of 64 rows
  int js = bid >> 7;       // JSPLIT splits
  int i0 = ib * 64;
  int wd = t >> 6, l = t & 63;
  int g = l >> 4, r16 = l & 15;
  int wrow0 = i0 + wd * 16;

  const ushort* arow = xb + (size_t)(wrow0 + r16) * NC + g * 8;
  short8 a0 = *(const short8*)(arow);
  short8 a1 = *(const short8*)(arow + 32);

  // swizzled read chunk offsets (elems), loop-invariant
  int sw = r16 & 7;
  int c0off = ((g ^ sw) << 3);
  int c1off = (((g + 4) ^ sw) << 3);

  float s[4] = {0.0f, 0.0f, 0.0f, 0.0f};

  const int NTL = NROWS / JSPLIT / TJ;  // 8 tiles
  for (int jt = 0; jt < NTL; ++jt) {
    int j0 = js * (NROWS / JSPLIT) + jt * TJ;
    __syncthreads();
    {
      int row = t >> 3, ch = t & 7;
      int chs = (ch ^ (row & 7)) << 3;       // swizzled chunk slot
      *(short8*)&Xj[row * PITCH + chs] =
          *(const short8*)(xb + (((size_t)(j0 + row)) << 6) + ch * 8);
      int row2 = row + 32;                   // (row+32)&7 == row&7
      *(short8*)&Xj[row2 * PITCH + chs] =
          *(const short8*)(xb + (((size_t)(j0 + row2)) << 6) + ch * 8);
    }
    __syncthreads();

    f32x4 acc[4];
#pragma unroll
    for (int fn = 0; fn < 4; ++fn) {
      int rbase = (fn * 16 + r16) * PITCH;
      short8 b0 = *(const short8*)&Xj[rbase + c0off];
      short8 b1 = *(const short8*)&Xj[rbase + c1off];
      f32x4 cz = {-KHI, -KHI, -KHI, -KHI};   // fold global shift into C
      cz = __builtin_amdgcn_mfma_f32_16x16x32_bf16(a0, b0, cz, 0, 0, 0);
      cz = __builtin_amdgcn_mfma_f32_16x16x32_bf16(a1, b1, cz, 0, 0, 0);
      acc[fn] = cz;
    }

    bool dt = (j0 == i0);
#pragma unroll
    for (int r = 0; r < 4; ++r) {
      float v0 = acc[0][r], v1 = acc[1][r], v2 = acc[2][r], v3 = acc[3][r];
      if (dt && (r16 == g * 4 + r)) {   // diagonal lives at fn==wd
        if (wd == 0) v0 = -1e30f;
        else if (wd == 1) v1 = -1e30f;
        else if (wd == 2) v2 = -1e30f;
        else v3 = -1e30f;
      }
      float e0 = __builtin_amdgcn_exp2f(v0);
      float e1 = __builtin_amdgcn_exp2f(v1);
      float e2 = __builtin_amdgcn_exp2f(v2);
      float e3 = __builtin_amdgcn_exp2f(v3);
      s[r] += (e0 + e1) + (e2 + e3);
    }
  }

  // sum across the 16 lanes (same g) sharing these 4 rows
#pragma unroll
  for (int r = 0; r < 4; ++r) {
    float ss = s[r];
#pragma unroll
    for (int msk = 8; msk >= 1; msk >>= 1) ss += __shfl_xor(ss, msk);
    if (r16 == 0) spart[js * NROWS + wrow0 + g * 4 + r] = ss;
  }
}

// ---- merge splits + positive-pair term + final combine (last block) ----
__global__ __launch_bounds__(256) void k_merge(const float* __restrict__ x,
                                               const int* __restrict__ tgt,
                                               const float* __restrict__ S,
                                               const int* __restrict__ cnt,
                                               const float* __restrict__ spart,
                                               float* __restrict__ ce_sum,
                                               float* __restrict__ sc_sum,
                                               int* __restrict__ done,
                                               float* __restrict__ out) {
  int i = blockIdx.x * 256 + threadIdx.x;
  float ssum = 0.0f;
#pragma unroll
  for (int p = 0; p < JSPLIT; ++p) ssum += spart[p * NROWS + i];
  float lse = LN2F * (KHI + __log2f(ssum));   // natural-log lse

  int L = tgt[i];
  const float4* xr = (const float4*)(x + (long)i * NC);
  const float4* Sr = (const float4*)(S + L * NC);
  float pd = 0.0f, n2 = 0.0f;
#pragma unroll
  for (int k = 0; k < 16; ++k) {
    float4 xv = xr[k], sv = Sr[k];
    pd += xv.x * sv.x + xv.y * sv.y + xv.z * sv.z + xv.w * sv.w;
    n2 += xv.x * xv.x + xv.y * xv.y + xv.z * xv.z + xv.w * xv.w;
  }
  int np = cnt[L] - 1;
  float per = (np > 0) ? (lse - (pd - n2) * INVT / (float)np) : 0.0f;
#pragma unroll
  for (int msk = 32; msk >= 1; msk >>= 1) per += __shfl_xor(per, msk);
  if ((threadIdx.x & 63) == 0) atomicAdd(sc_sum, per);

  // last-finishing block computes the final scalar
  __threadfence();
  __syncthreads();
  if (threadIdx.x == 0) {
    int prev = atomicAdd(done, 1);
    if (prev == (int)gridDim.x - 1) {
      __threadfence();
      float ce = atomicAdd(ce_sum, 0.0f);
      float sc = atomicAdd(sc_sum, 0.0f);
      out[0] = (1.0f - LMBDA) * (ce / (float)NROWS) + LMBDA * sc;
    }
  }
}

extern "C" void kernel_launch(void* const* d_in, const int* in_sizes, int n_in,
                              void* d_out, int out_size, void* d_ws, size_t ws_size,
                              hipStream_t stream) {
  const float* x = (const float*)d_in[0];
  const int* tgt = (const int*)d_in[1];
  float* ws = (float*)d_ws;
  float* S = ws + WS_S;
  int* cnt = (int*)(ws + WS_CNT);
  float* ce_sum = ws + WS_CE;
  float* sc_sum = ws + WS_SC;
  int* done = (int*)(ws + WS_DONE);
  float* spart = ws + WS_SPART;
  ushort* xb = (ushort*)(ws + WS_XB);
  float* out = (float*)d_out;

  k_zero<<<5, 256, 0, stream>>>(ws);
  k_pre<<<128, 256, 0, stream>>>(x, tgt, xb, S, cnt, ce_sum);
  k_sim<<<128 * JSPLIT, 256, 0, stream>>>(xb, spart);
  k_merge<<<32, 256, 0, stream>>>(x, tgt, S, cnt, spart,
                                  ce_sum, sc_sum, done, out);
}

// Round 6
// 59.720 us; speedup vs baseline: 1.1230x; 1.1230x over previous
//
#include <hip/hip_runtime.h>

#define NROWS 8192
#define NC 64
#define INVT 2.0f      // 1 / TEMPERATURE
#define LMBDA 0.5f
#define JSPLIT 16
#define BI 128         // i-rows per block (4 waves x 32 rows)
#define TJ 64
#define PITCH 72       // LDS row pitch in bf16 elems (144 B)
#define LN2F 0.69314718055994531f
#define L2EF 1.4426950408889634f
#define KHI 110.0f     // global log2-domain shift: exp2(dot_scaled - KHI)

typedef __attribute__((ext_vector_type(8))) short short8;
typedef __attribute__((ext_vector_type(4))) float f32x4;

// ---------------- workspace layout (float slots) ----------------
#define WS_S     0                        // 64x64 class sums
#define WS_CNT   4096                     // 64 ints
#define WS_CE    4160
#define WS_SC    4161
#define WS_DONE  4162
#define WS_SPART 4224                     // JSPLIT * 8192 floats
#define WS_XB    (WS_SPART + JSPLIT*NROWS)  // 8192*64 ushort
#define WS_ZERO_F4 1041                   // ceil(4163/4) float4s

__device__ inline ushort f2bf(float f) {
  uint b = __float_as_uint(f);
  return (ushort)((b + 0x7fffu + ((b >> 16) & 1u)) >> 16);
}

// ---- zero the accumulator scalars / S / cnt ----
__global__ void k_zero(float* __restrict__ ws) {
  int i = blockIdx.x * 256 + threadIdx.x;
  if (i < WS_ZERO_F4) ((float4*)ws)[i] = make_float4(0.f, 0.f, 0.f, 0.f);
}

// ---- fused: bf16 convert (scaled), class sums/counts, cross entropy ----
// (R4-measured config: 64 blocks x 512 threads, 2 threads/row)
__global__ __launch_bounds__(512) void k_pre(const float* __restrict__ x,
                                             const int* __restrict__ tgt,
                                             ushort* __restrict__ xb,
                                             float* __restrict__ S,
                                             int* __restrict__ cnt,
                                             float* __restrict__ ce_sum) {
  __shared__ float Sl[NC * NC];
  __shared__ int cl[NC];
  int t = threadIdx.x;
  for (int i = t; i < NC * NC; i += 512) Sl[i] = 0.0f;
  if (t < NC) cl[t] = 0;
  __syncthreads();

  int hr = t >> 1, half = t & 1;
  int row = blockIdx.x * 256 + hr;
  int lbl = tgt[row];
  const float* xp = x + (size_t)row * NC + half * 32;
  float4 b[8];
#pragma unroll
  for (int k = 0; k < 8; ++k) b[k] = ((const float4*)xp)[k];

  // scaled bf16: xs = x * sqrt(INVT * log2(e))
  const float c = 1.6986436005760381f;
  ushort us[32];
#pragma unroll
  for (int k = 0; k < 8; ++k) {
    us[k * 4 + 0] = f2bf(b[k].x * c); us[k * 4 + 1] = f2bf(b[k].y * c);
    us[k * 4 + 2] = f2bf(b[k].z * c); us[k * 4 + 3] = f2bf(b[k].w * c);
  }
  ushort* xq = xb + (size_t)row * NC + half * 32;
#pragma unroll
  for (int k = 0; k < 4; ++k) ((short8*)xq)[k] = ((const short8*)us)[k];

  // class sums (LDS atomics)
#pragma unroll
  for (int k = 0; k < 8; ++k) {
    int c0 = half * 32 + k * 4;
    atomicAdd(&Sl[lbl * NC + c0 + 0], b[k].x);
    atomicAdd(&Sl[lbl * NC + c0 + 1], b[k].y);
    atomicAdd(&Sl[lbl * NC + c0 + 2], b[k].z);
    atomicAdd(&Sl[lbl * NC + c0 + 3], b[k].w);
  }
  if (!half) atomicAdd(&cl[lbl], 1);

  // cross entropy (2 threads per row), base-2 domain
  float m = -1e30f;
#pragma unroll
  for (int k = 0; k < 8; ++k)
    m = fmaxf(m, fmaxf(fmaxf(b[k].x, b[k].y), fmaxf(b[k].z, b[k].w)));
  m = fmaxf(m, __shfl_xor(m, 1));
  float mb = m * L2EF;
  float s = 0.0f, tl = 0.0f;
#pragma unroll
  for (int k = 0; k < 8; ++k) {
    s += __builtin_amdgcn_exp2f(fmaf(b[k].x, L2EF, -mb)) +
         __builtin_amdgcn_exp2f(fmaf(b[k].y, L2EF, -mb)) +
         __builtin_amdgcn_exp2f(fmaf(b[k].z, L2EF, -mb)) +
         __builtin_amdgcn_exp2f(fmaf(b[k].w, L2EF, -mb));
    int c0 = half * 32 + k * 4;
    if (lbl == c0 + 0) tl = b[k].x;
    if (lbl == c0 + 1) tl = b[k].y;
    if (lbl == c0 + 2) tl = b[k].z;
    if (lbl == c0 + 3) tl = b[k].w;
  }
  s += __shfl_xor(s, 1);
  tl += __shfl_xor(tl, 1);
  float ce = (half == 0) ? (m + LN2F * __log2f(s) - tl) : 0.0f;
#pragma unroll
  for (int msk = 32; msk >= 1; msk >>= 1) ce += __shfl_xor(ce, msk);
  if ((t & 63) == 0) atomicAdd(ce_sum, ce);

  __syncthreads();
  for (int i = t; i < NC * NC; i += 512) atomicAdd(&S[i], Sl[i]);
  if (t < NC && cl[t]) atomicAdd(&cnt[t], cl[t]);
}

// ---- main pass: MFMA sim tiles (32 i-rows/wave), conflict-free LDS ----
// slot(row, ch) = (ch + (row>>1)) & 7 : quarter-wave 2-way on read & write
__global__ __launch_bounds__(256, 4) void k_sim(const ushort* __restrict__ xb,
                                                float* __restrict__ spart) {
  __shared__ ushort Xj[TJ * PITCH];
  int t = threadIdx.x;
  int bid = blockIdx.x;
  int ib = bid & 63;       // 64 i-blocks of 128 rows
  int js = bid >> 6;       // JSPLIT splits
  int i0 = ib * BI;
  int wd = t >> 6, l = t & 63;
  int g = l >> 4, r16 = l & 15;
  int wrow0 = i0 + wd * 32;

  // A fragments: 2 row-sets (16 rows each) x 2 k-chunks
  const ushort* ar0 = xb + (size_t)(wrow0 + r16) * NC + g * 8;
  const ushort* ar1 = xb + (size_t)(wrow0 + 16 + r16) * NC + g * 8;
  short8 a00 = *(const short8*)(ar0);
  short8 a01 = *(const short8*)(ar0 + 32);
  short8 a10 = *(const short8*)(ar1);
  short8 a11 = *(const short8*)(ar1 + 32);

  // conflict-free swizzled read chunk offsets (elems), loop-invariant
  int c0off = ((g + (r16 >> 1)) & 7) << 3;
  int c1off = ((g + 4 + (r16 >> 1)) & 7) << 3;

  // diagonal lane predicates (which acc element is on the diagonal)
  int lr = r16 - g * 4;    // in [0,4) iff this lane holds a diag element

  float s0[4] = {0.f, 0.f, 0.f, 0.f};
  float s1[4] = {0.f, 0.f, 0.f, 0.f};

  const int NTL = NROWS / JSPLIT / TJ;  // 8 tiles
  for (int jt = 0; jt < NTL; ++jt) {
    int j0 = js * (NROWS / JSPLIT) + jt * TJ;
    __syncthreads();
    {
      int row = t >> 3, ch = t & 7;
      int slot = ((ch + (row >> 1)) & 7) << 3;   // (row+32)>>1 same mod 8
      *(short8*)&Xj[row * PITCH + slot] =
          *(const short8*)(xb + (((size_t)(j0 + row)) << 6) + ch * 8);
      int row2 = row + 32;
      *(short8*)&Xj[row2 * PITCH + slot] =
          *(const short8*)(xb + (((size_t)(j0 + row2)) << 6) + ch * 8);
    }
    __syncthreads();

    short8 b0[4], b1[4];
#pragma unroll
    for (int fn = 0; fn < 4; ++fn) {
      int rbase = (fn * 16 + r16) * PITCH;
      b0[fn] = *(const short8*)&Xj[rbase + c0off];
      b1[fn] = *(const short8*)&Xj[rbase + c1off];
    }

    int d0 = (wrow0 - j0) >> 4;   // wave-uniform diag subtile index

#pragma unroll
    for (int fn = 0; fn < 4; ++fn) {
      // fragset 0: rows wrow0 .. wrow0+15
      f32x4 cz = {-KHI, -KHI, -KHI, -KHI};
      cz = __builtin_amdgcn_mfma_f32_16x16x32_bf16(a00, b0[fn], cz, 0, 0, 0);
      cz = __builtin_amdgcn_mfma_f32_16x16x32_bf16(a01, b1[fn], cz, 0, 0, 0);
      if (d0 == fn) {              // uniform branch, rare
        cz[0] = (lr == 0) ? -1e30f : cz[0];
        cz[1] = (lr == 1) ? -1e30f : cz[1];
        cz[2] = (lr == 2) ? -1e30f : cz[2];
        cz[3] = (lr == 3) ? -1e30f : cz[3];
      }
      s0[0] += __builtin_amdgcn_exp2f(cz[0]);
      s0[1] += __builtin_amdgcn_exp2f(cz[1]);
      s0[2] += __builtin_amdgcn_exp2f(cz[2]);
      s0[3] += __builtin_amdgcn_exp2f(cz[3]);

      // fragset 1: rows wrow0+16 .. wrow0+31
      f32x4 cw = {-KHI, -KHI, -KHI, -KHI};
      cw = __builtin_amdgcn_mfma_f32_16x16x32_bf16(a10, b0[fn], cw, 0, 0, 0);
      cw = __builtin_amdgcn_mfma_f32_16x16x32_bf16(a11, b1[fn], cw, 0, 0, 0);
      if (d0 == fn - 1) {          // uniform branch, rare
        cw[0] = (lr == 0) ? -1e30f : cw[0];
        cw[1] = (lr == 1) ? -1e30f : cw[1];
        cw[2] = (lr == 2) ? -1e30f : cw[2];
        cw[3] = (lr == 3) ? -1e30f : cw[3];
      }
      s1[0] += __builtin_amdgcn_exp2f(cw[0]);
      s1[1] += __builtin_amdgcn_exp2f(cw[1]);
      s1[2] += __builtin_amdgcn_exp2f(cw[2]);
      s1[3] += __builtin_amdgcn_exp2f(cw[3]);
    }
  }

  // sum across the 16 lanes (same g) sharing these rows; write both fragsets
#pragma unroll
  for (int r = 0; r < 4; ++r) {
    float ssa = s0[r], ssb = s1[r];
#pragma unroll
    for (int msk = 8; msk >= 1; msk >>= 1) {
      ssa += __shfl_xor(ssa, msk);
      ssb += __shfl_xor(ssb, msk);
    }
    if (r16 == 0) {
      spart[js * NROWS + wrow0 + g * 4 + r] = ssa;
      spart[js * NROWS + wrow0 + 16 + g * 4 + r] = ssb;
    }
  }
}

// ---- merge splits + positive-pair term + final combine (last block) ----
__global__ __launch_bounds__(256) void k_merge(const float* __restrict__ x,
                                               const int* __restrict__ tgt,
                                               const float* __restrict__ S,
                                               const int* __restrict__ cnt,
                                               const float* __restrict__ spart,
                                               float* __restrict__ ce_sum,
                                               float* __restrict__ sc_sum,
                                               int* __restrict__ done,
                                               float* __restrict__ out) {
  int i = blockIdx.x * 256 + threadIdx.x;
  float ssum = 0.0f;
#pragma unroll
  for (int p = 0; p < JSPLIT; ++p) ssum += spart[p * NROWS + i];
  float lse = LN2F * (KHI + __log2f(ssum));   // natural-log lse

  int L = tgt[i];
  const float4* xr = (const float4*)(x + (long)i * NC);
  const float4* Sr = (const float4*)(S + L * NC);
  float pd = 0.0f, n2 = 0.0f;
#pragma unroll
  for (int k = 0; k < 16; ++k) {
    float4 xv = xr[k], sv = Sr[k];
    pd += xv.x * sv.x + xv.y * sv.y + xv.z * sv.z + xv.w * sv.w;
    n2 += xv.x * xv.x + xv.y * xv.y + xv.z * xv.z + xv.w * xv.w;
  }
  int np = cnt[L] - 1;
  float per = (np > 0) ? (lse - (pd - n2) * INVT / (float)np) : 0.0f;
#pragma unroll
  for (int msk = 32; msk >= 1; msk >>= 1) per += __shfl_xor(per, msk);
  if ((threadIdx.x & 63) == 0) atomicAdd(sc_sum, per);

  // last-finishing block computes the final scalar
  __threadfence();
  __syncthreads();
  if (threadIdx.x == 0) {
    int prev = atomicAdd(done, 1);
    if (prev == (int)gridDim.x - 1) {
      __threadfence();
      float ce = atomicAdd(ce_sum, 0.0f);
      float sc = atomicAdd(sc_sum, 0.0f);
      out[0] = (1.0f - LMBDA) * (ce / (float)NROWS) + LMBDA * sc;
    }
  }
}

extern "C" void kernel_launch(void* const* d_in, const int* in_sizes, int n_in,
                              void* d_out, int out_size, void* d_ws, size_t ws_size,
                              hipStream_t stream) {
  const float* x = (const float*)d_in[0];
  const int* tgt = (const int*)d_in[1];
  float* ws = (float*)d_ws;
  float* S = ws + WS_S;
  int* cnt = (int*)(ws + WS_CNT);
  float* ce_sum = ws + WS_CE;
  float* sc_sum = ws + WS_SC;
  int* done = (int*)(ws + WS_DONE);
  float* spart = ws + WS_SPART;
  ushort* xb = (ushort*)(ws + WS_XB);
  float* out = (float*)d_out;

  k_zero<<<5, 256, 0, stream>>>(ws);
  k_pre<<<32, 512, 0, stream>>>(x, tgt, xb, S, cnt, ce_sum);
  k_sim<<<64 * JSPLIT, 256, 0, stream>>>(xb, spart);
  k_merge<<<32, 256, 0, stream>>>(x, tgt, S, cnt, spart,
                                  ce_sum, sc_sum, done, out);
}

// Round 7
// 46.563 us; speedup vs baseline: 1.4403x; 1.2826x over previous
//
#include <hip/hip_runtime.h>

#define NROWS 8192
#define NC 64
#define INVT 2.0f      // 1 / TEMPERATURE
#define LMBDA 0.5f
#define JSPLIT 16
#define NIB 32         // i-blocks (8192 / 256)
#define TJ 64
#define PITCH 72       // LDS row pitch in bf16 elems (144 B)
#define LN2F 0.69314718055994531f
#define L2EF 1.4426950408889634f
#define KHI 110.0f     // global log2-domain shift: exp2(dot_scaled - KHI)
#define NPRE 64        // k_pre blocks

typedef __attribute__((ext_vector_type(8))) short short8;
typedef __attribute__((ext_vector_type(4))) float f32x4;

// ---------------- workspace layout (float slots) ----------------
#define WS_SC    0
#define WS_DONE  1
#define WS_S     64                       // 4096 final class sums
#define WS_CNT   (WS_S + 4096)            // 64 ints
#define WS_CEP   (WS_CNT + 64)            // NPRE ce partials
#define WS_CNTP  (WS_CEP + NPRE)          // NPRE*64 ints
#define WS_SPRE  (WS_CNTP + NPRE*64)      // NPRE*4096 S partials
#define WS_SPART (WS_SPRE + NPRE*4096)    // JSPLIT*NROWS exp-sum partials
#define WS_XB    (WS_SPART + JSPLIT*NROWS)

__device__ inline ushort f2bf(float f) {
  uint b = __float_as_uint(f);
  return (ushort)((b + 0x7fffu + ((b >> 16) & 1u)) >> 16);
}

// ---- fused: bf16 convert (scaled), partial class sums/counts, CE ----
// 64 blocks x 512 threads, 4 threads/row (R4-proven). Plain stores only.
__global__ __launch_bounds__(512) void k_pre(const float* __restrict__ x,
                                             const int* __restrict__ tgt,
                                             ushort* __restrict__ xb,
                                             float* __restrict__ Spre,
                                             int* __restrict__ cntp,
                                             float* __restrict__ cep,
                                             float* __restrict__ ws) {
  __shared__ float Sl[NC * NC];
  __shared__ int cl[NC];
  __shared__ float ceb;
  int t = threadIdx.x;
  int bid = blockIdx.x;
  if (bid == 0 && t == 0) { ws[WS_SC] = 0.0f; ((int*)ws)[WS_DONE] = 0; }
  for (int i = t; i < NC * NC; i += 512) Sl[i] = 0.0f;
  if (t < NC) cl[t] = 0;
  if (t == 0) ceb = 0.0f;
  __syncthreads();

  int r4 = t >> 2, q = t & 3;            // 4 threads per row, 16 floats each
  int row = bid * 128 + r4;
  int lbl = tgt[row];
  const float* xp = x + (size_t)row * NC + q * 16;
  float4 b[4];
#pragma unroll
  for (int k = 0; k < 4; ++k) b[k] = ((const float4*)xp)[k];

  // scaled bf16: xs = x * sqrt(INVT * log2(e))
  const float c = 1.6986436005760381f;
  ushort us[16];
#pragma unroll
  for (int k = 0; k < 4; ++k) {
    us[k * 4 + 0] = f2bf(b[k].x * c); us[k * 4 + 1] = f2bf(b[k].y * c);
    us[k * 4 + 2] = f2bf(b[k].z * c); us[k * 4 + 3] = f2bf(b[k].w * c);
  }
  ushort* xq = xb + (size_t)row * NC + q * 16;
  ((short8*)xq)[0] = ((const short8*)us)[0];
  ((short8*)xq)[1] = ((const short8*)us)[1];

  // class sums (LDS atomics)
#pragma unroll
  for (int k = 0; k < 4; ++k) {
    int c0 = q * 16 + k * 4;
    atomicAdd(&Sl[lbl * NC + c0 + 0], b[k].x);
    atomicAdd(&Sl[lbl * NC + c0 + 1], b[k].y);
    atomicAdd(&Sl[lbl * NC + c0 + 2], b[k].z);
    atomicAdd(&Sl[lbl * NC + c0 + 3], b[k].w);
  }
  if (q == 0) atomicAdd(&cl[lbl], 1);

  // cross entropy (4 threads per row), base-2 domain
  float m = -1e30f;
#pragma unroll
  for (int k = 0; k < 4; ++k)
    m = fmaxf(m, fmaxf(fmaxf(b[k].x, b[k].y), fmaxf(b[k].z, b[k].w)));
  m = fmaxf(m, __shfl_xor(m, 1));
  m = fmaxf(m, __shfl_xor(m, 2));
  float mb = m * L2EF;
  float s = 0.0f, tl = 0.0f;
#pragma unroll
  for (int k = 0; k < 4; ++k) {
    s += __builtin_amdgcn_exp2f(fmaf(b[k].x, L2EF, -mb)) +
         __builtin_amdgcn_exp2f(fmaf(b[k].y, L2EF, -mb)) +
         __builtin_amdgcn_exp2f(fmaf(b[k].z, L2EF, -mb)) +
         __builtin_amdgcn_exp2f(fmaf(b[k].w, L2EF, -mb));
    int c0 = q * 16 + k * 4;
    if (lbl == c0 + 0) tl = b[k].x;
    if (lbl == c0 + 1) tl = b[k].y;
    if (lbl == c0 + 2) tl = b[k].z;
    if (lbl == c0 + 3) tl = b[k].w;
  }
  s += __shfl_xor(s, 1);  s += __shfl_xor(s, 2);
  tl += __shfl_xor(tl, 1); tl += __shfl_xor(tl, 2);
  float ce = (q == 0) ? (m + LN2F * __log2f(s) - tl) : 0.0f;
#pragma unroll
  for (int msk = 32; msk >= 1; msk >>= 1) ce += __shfl_xor(ce, msk);
  if ((t & 63) == 0) atomicAdd(&ceb, ce);

  __syncthreads();
  // plain-store partials
  {
    float4* dst = (float4*)(Spre + (size_t)bid * 4096);
    const float4* src = (const float4*)Sl;
    dst[t] = src[t];
    dst[t + 512] = src[t + 512];
  }
  if (t < NC) cntp[bid * NC + t] = cl[t];
  if (t == 0) cep[bid] = ceb;
}

// ---- main pass: MFMA sim tiles (64 i-rows/wave), conflict-free LDS ----
// Blocks 0..16 additionally reduce k_pre partials into final S / cnt.
__global__ __launch_bounds__(256, 2) void k_sim(const ushort* __restrict__ xb,
                                                float* __restrict__ spart,
                                                const float* __restrict__ Spre,
                                                float* __restrict__ S,
                                                const int* __restrict__ cntp,
                                                int* __restrict__ cnt) {
  __shared__ ushort Xj[TJ * PITCH];
  int t = threadIdx.x;
  int bid = blockIdx.x;

  // helper reductions (visible to k_merge via kernel boundary)
  if (bid < 16) {
    int e = bid * 256 + t;
    float a = 0.0f;
#pragma unroll 8
    for (int b = 0; b < NPRE; ++b) a += Spre[b * 4096 + e];
    S[e] = a;
  } else if (bid == 16 && t < NC) {
    int a = 0;
#pragma unroll 8
    for (int b = 0; b < NPRE; ++b) a += cntp[b * NC + t];
    cnt[t] = a;
  }

  int ib = bid & (NIB - 1);   // 32 i-blocks of 256 rows
  int js = bid >> 5;          // JSPLIT splits
  int i0 = ib * 256;
  int wd = t >> 6, l = t & 63;
  int g = l >> 4, r16 = l & 15;
  int wrow0 = i0 + wd * 64;   // wave owns 64 i-rows
  int lr = r16 - g * 4;       // element idx on diagonal if in [0,4)

  // A fragments: 4 row-sets (16 rows each) x 2 k-chunks = 32 VGPRs
  short8 aF[4][2];
#pragma unroll
  for (int fs = 0; fs < 4; ++fs) {
    const ushort* ar = xb + (size_t)(wrow0 + fs * 16 + r16) * NC + g * 8;
    aF[fs][0] = *(const short8*)(ar);
    aF[fs][1] = *(const short8*)(ar + 32);
  }

  // conflict-free swizzled read chunk offsets (elems), loop-invariant
  int c0off = ((g + (r16 >> 1)) & 7) << 3;
  int c1off = ((g + 4 + (r16 >> 1)) & 7) << 3;

  float s[4][4];
#pragma unroll
  for (int fs = 0; fs < 4; ++fs)
#pragma unroll
    for (int r = 0; r < 4; ++r) s[fs][r] = 0.0f;

  const int NTL = NROWS / JSPLIT / TJ;  // 8 tiles
  for (int jt = 0; jt < NTL; ++jt) {
    int j0 = js * (NROWS / JSPLIT) + jt * TJ;
    __syncthreads();
    {
      int row = t >> 3, ch = t & 7;
      int slot = ((ch + (row >> 1)) & 7) << 3;   // (row+32)>>1 same mod 8
      *(short8*)&Xj[row * PITCH + slot] =
          *(const short8*)(xb + (((size_t)(j0 + row)) << 6) + ch * 8);
      int row2 = row + 32;
      *(short8*)&Xj[row2 * PITCH + slot] =
          *(const short8*)(xb + (((size_t)(j0 + row2)) << 6) + ch * 8);
    }
    __syncthreads();

    short8 b0[4], b1[4];
#pragma unroll
    for (int fn = 0; fn < 4; ++fn) {
      int rbase = (fn * 16 + r16) * PITCH;
      b0[fn] = *(const short8*)&Xj[rbase + c0off];
      b1[fn] = *(const short8*)&Xj[rbase + c1off];
    }

    bool dt = (j0 == wrow0);   // wave's rows intersect this j-tile's diagonal

#pragma unroll
    for (int fs = 0; fs < 4; ++fs) {
#pragma unroll
      for (int fn = 0; fn < 4; ++fn) {
        f32x4 cz = {-KHI, -KHI, -KHI, -KHI};
        cz = __builtin_amdgcn_mfma_f32_16x16x32_bf16(aF[fs][0], b0[fn], cz, 0, 0, 0);
        cz = __builtin_amdgcn_mfma_f32_16x16x32_bf16(aF[fs][1], b1[fn], cz, 0, 0, 0);
        if (dt && fs == fn) {            // uniform branch, rare
          cz[0] = (lr == 0) ? -1e30f : cz[0];
          cz[1] = (lr == 1) ? -1e30f : cz[1];
          cz[2] = (lr == 2) ? -1e30f : cz[2];
          cz[3] = (lr == 3) ? -1e30f : cz[3];
        }
        s[fs][0] += __builtin_amdgcn_exp2f(cz[0]);
        s[fs][1] += __builtin_amdgcn_exp2f(cz[1]);
        s[fs][2] += __builtin_amdgcn_exp2f(cz[2]);
        s[fs][3] += __builtin_amdgcn_exp2f(cz[3]);
      }
    }
  }

  // sum across the 16 lanes (same g) sharing each row; write spart
#pragma unroll
  for (int fs = 0; fs < 4; ++fs) {
#pragma unroll
    for (int r = 0; r < 4; ++r) {
      float ss = s[fs][r];
#pragma unroll
      for (int msk = 8; msk >= 1; msk >>= 1) ss += __shfl_xor(ss, msk);
      if (r16 == 0) spart[js * NROWS + wrow0 + fs * 16 + g * 4 + r] = ss;
    }
  }
}

// ---- merge splits + positive-pair term + final combine (last block) ----
__global__ __launch_bounds__(256) void k_merge(const float* __restrict__ x,
                                               const int* __restrict__ tgt,
                                               const float* __restrict__ S,
                                               const int* __restrict__ cnt,
                                               const float* __restrict__ spart,
                                               const float* __restrict__ cep,
                                               float* __restrict__ ws,
                                               float* __restrict__ out) {
  __shared__ int lastf;
  float* sc_sum = ws + WS_SC;
  int* done = (int*)ws + WS_DONE;
  int t = threadIdx.x;
  int i = blockIdx.x * 256 + t;

  float ssum = 0.0f;
#pragma unroll
  for (int p = 0; p < JSPLIT; ++p) ssum += spart[p * NROWS + i];
  float lse = LN2F * (KHI + __log2f(ssum));   // natural-log lse

  int L = tgt[i];
  const float4* xr = (const float4*)(x + (size_t)i * NC);
  const float4* Sr = (const float4*)(S + L * NC);
  float pd = 0.0f, n2 = 0.0f;
#pragma unroll
  for (int k = 0; k < 16; ++k) {
    float4 xv = xr[k], sv = Sr[k];
    pd += xv.x * sv.x + xv.y * sv.y + xv.z * sv.z + xv.w * sv.w;
    n2 += xv.x * xv.x + xv.y * xv.y + xv.z * xv.z + xv.w * xv.w;
  }
  int np = cnt[L] - 1;
  float per = (np > 0) ? (lse - (pd - n2) * INVT / (float)np) : 0.0f;
#pragma unroll
  for (int msk = 32; msk >= 1; msk >>= 1) per += __shfl_xor(per, msk);
  if ((t & 63) == 0) atomicAdd(sc_sum, per);

  // last-finishing block computes the final scalar
  __threadfence();
  __syncthreads();
  if (t == 0) lastf = (atomicAdd(done, 1) == (int)gridDim.x - 1) ? 1 : 0;
  __syncthreads();
  if (lastf && t < 64) {
    __threadfence();
    float cv = cep[t];
#pragma unroll
    for (int msk = 32; msk >= 1; msk >>= 1) cv += __shfl_xor(cv, msk);
    if (t == 0) {
      float sc = atomicAdd(sc_sum, 0.0f);
      out[0] = (1.0f - LMBDA) * (cv / (float)NROWS) + LMBDA * sc;
    }
  }
}

extern "C" void kernel_launch(void* const* d_in, const int* in_sizes, int n_in,
                              void* d_out, int out_size, void* d_ws, size_t ws_size,
                              hipStream_t stream) {
  const float* x = (const float*)d_in[0];
  const int* tgt = (const int*)d_in[1];
  float* ws = (float*)d_ws;
  float* S = ws + WS_S;
  int* cnt = (int*)(ws + WS_CNT);
  float* cep = ws + WS_CEP;
  int* cntp = (int*)(ws + WS_CNTP);
  float* Spre = ws + WS_SPRE;
  float* spart = ws + WS_SPART;
  ushort* xb = (ushort*)(ws + WS_XB);
  float* out = (float*)d_out;

  k_pre<<<NPRE, 512, 0, stream>>>(x, tgt, xb, Spre, cntp, cep, ws);
  k_sim<<<NIB * JSPLIT, 256, 0, stream>>>(xb, spart, Spre, S, cntp, cnt);
  k_merge<<<32, 256, 0, stream>>>(x, tgt, S, cnt, spart, cep, ws, out);
}